// Round 6
// baseline (400.847 us; speedup 1.0000x reference)
//
#include <hip/hip_runtime.h>

// toy_gnn scatter-add: out[dst[e], f] += w_mp * edge_weight[e] * x[src[e], f]
// N=100000, E=1600000, F=32, fp32.
//
// Round 6: coarse bin (256-node buckets, dense 84B runs) + fused no-sort
// gather (4 sub-blocks per bucket = 1564 blocks).
//   R5 lessons: (a) the 43us fillBufferAligned is the harness ws re-poison,
//   inside the timed window -- fixed tax; (b) NPB=64 binning regressed to
//   21B runs (partial-sector write amp); (c) per-node gather pays
//   max(deg)/mean(deg) ~ 1.6x wave imbalance. Now: bin coarse (R4 shape),
//   gather compacts its quarter of records via wave-aggregated atomics and
//   accumulates through rotated-LDS ds_add_f32 -- no sort passes, perfectly
//   balanced groups, zero global fp32 atomics.

constexpr int N_NODES = 100000;
constexpr int N_EDGES = 1600000;
constexpr int F_DIM   = 32;

// ---- binning (coarse) ----
constexpr int NPB_C = 256;                           // nodes per coarse bucket
constexpr int NB_C  = (N_NODES + NPB_C - 1) / NPB_C; // 391
constexpr int CAP_C = 4608;                          // mean 4096 + 8 sigma(64)

constexpr int BIN_THREADS = 512;
constexpr int BIN_EPT     = 8;
constexpr int BIN_CHUNK   = BIN_THREADS * BIN_EPT;                  // 4096
constexpr int BIN_BLOCKS  = (N_EDGES + BIN_CHUNK - 1) / BIN_CHUNK;  // 391

// ---- gather (fine) ----
constexpr int SUBS    = 4;                           // sub-blocks per coarse bucket
constexpr int NPB_F   = NPB_C / SUBS;                // 64 nodes per sub-tile
constexpr int MCAP    = 1344;                        // mean 1024 + 10 sigma(32)
constexpr int AGG_THREADS = 512;

// ---------------- workspace layout (bytes) ----------------
constexpr size_t WS_CURSOR  = 0;                     // NB_C ints
constexpr size_t WS_RECORDS = 4096;                  // NB_C*CAP_C uint2
constexpr size_t WS_NEEDED  = WS_RECORDS + (size_t)NB_C * CAP_C * 8;  // ~14.4 MB

__global__ __launch_bounds__(256) void init_cursors(int* __restrict__ gcursor)
{
    int i = blockIdx.x * 256 + threadIdx.x;
    if (i < NB_C) gcursor[i] = i * CAP_C;
}

__global__ __launch_bounds__(BIN_THREADS) void bin_edges(
    const int* __restrict__ src, const int* __restrict__ dst,
    const float* __restrict__ ew, const float* __restrict__ w_mp,
    int* __restrict__ gcursor, uint2* __restrict__ records)
{
    __shared__ int lhist[NB_C];
    __shared__ int lbase[NB_C];
    if (threadIdx.x < NB_C) lhist[threadIdx.x] = 0;
    __syncthreads();

    const float w = w_mp[0];
    const int base_e = blockIdx.x * BIN_CHUNK;
    int   bkt[BIN_EPT];
    uint2 rec[BIN_EPT];

    #pragma unroll
    for (int i = 0; i < BIN_EPT; ++i) {
        int e = base_e + threadIdx.x + i * BIN_THREADS;
        bkt[i] = -1;
        if (e < N_EDGES) {
            int d = dst[e];
            int b = d >> 8;                     // coarse bucket (256 nodes)
            bkt[i] = b;
            rec[i].x = __float_as_uint(w * ew[e]);
            rec[i].y = (unsigned)src[e] | ((unsigned)(d & 255) << 24);
            atomicAdd(&lhist[b], 1);
        }
    }
    __syncthreads();

    if (threadIdx.x < NB_C) {
        int c = lhist[threadIdx.x];
        lbase[threadIdx.x] = c ? atomicAdd(&gcursor[threadIdx.x], c) : 0;
        lhist[threadIdx.x] = 0;
    }
    __syncthreads();

    #pragma unroll
    for (int i = 0; i < BIN_EPT; ++i) {
        int b = bkt[i];
        if (b >= 0) {
            int pos = lbase[b] + atomicAdd(&lhist[b], 1);
            if (pos < (b + 1) * CAP_C)          // overflow guard (8-sigma margin)
                records[pos] = rec[i];
        }
    }
}

__device__ __forceinline__ void tile_add(float* tile, int row, int q, int k, float v)
{
    __hip_atomic_fetch_add(&tile[(row << 5) + ((q + k + row) & 31)], v,
                           __ATOMIC_RELAXED, __HIP_MEMORY_SCOPE_WORKGROUP);
}

__global__ __launch_bounds__(AGG_THREADS) void gather_nosort(
    const int*   __restrict__ gcursor,
    const uint2* __restrict__ records,
    const float* __restrict__ x,
    float*       __restrict__ out)
{
    __shared__ float tile[NPB_F * F_DIM];   // 8 KB, rotated by row
    __shared__ uint2 mine[MCAP];            // 10.5 KB compacted records
    __shared__ int   mcount;

    const int coarse = blockIdx.x >> 2;
    const unsigned sub = blockIdx.x & 3;
    const int t = threadIdx.x;

    // zero tile + counter
    float4* t4 = reinterpret_cast<float4*>(tile);
    if (t < NPB_F * F_DIM / 4) t4[t] = make_float4(0.f, 0.f, 0.f, 0.f);
    if (t == 0) mcount = 0;
    __syncthreads();

    // compact this sub's records (wave-aggregated atomic slot allocation)
    const int rbase = coarse * CAP_C;
    const int cnt   = min(gcursor[coarse] - rbase, CAP_C);
    const int lane  = t & 63;
    for (int j = t; j < cnt; j += AGG_THREADS) {
        uint2 r = records[rbase + j];
        bool match = (r.y >> 30) == sub;        // dl>>6 == sub
        unsigned long long m = __ballot(match);
        if (m) {
            int lead = __ffsll((unsigned long long)m) - 1;
            int base = 0;
            if (lane == lead) base = atomicAdd(&mcount, __popcll(m));
            base = __shfl(base, lead, 64);
            if (match) {
                int slot = base + __popcll(m & ((1ull << lane) - 1));
                if (slot < MCAP) mine[slot] = r;   // 10-sigma margin
            }
        }
    }
    __syncthreads();

    // accumulate: 8 threads per record, ds_add_f32 into rotated tile.
    const int M = min(mcount, MCAP);
    const int q = (t & 7) * 4;
    int g = t >> 3;
    for (; g + 64 < M; g += 128) {               // 2-way unroll: 2 loads in flight
        uint2 r0 = mine[g];
        uint2 r1 = mine[g + 64];
        const float4 v0 = *reinterpret_cast<const float4*>(
            x + (size_t)(r0.y & 0xFFFFFFu) * F_DIM + q);
        const float4 v1 = *reinterpret_cast<const float4*>(
            x + (size_t)(r1.y & 0xFFFFFFu) * F_DIM + q);
        float c0 = __uint_as_float(r0.x);
        float c1 = __uint_as_float(r1.x);
        int row0 = (r0.y >> 24) & 63;
        int row1 = (r1.y >> 24) & 63;
        tile_add(tile, row0, q, 0, c0 * v0.x);
        tile_add(tile, row0, q, 1, c0 * v0.y);
        tile_add(tile, row0, q, 2, c0 * v0.z);
        tile_add(tile, row0, q, 3, c0 * v0.w);
        tile_add(tile, row1, q, 0, c1 * v1.x);
        tile_add(tile, row1, q, 1, c1 * v1.y);
        tile_add(tile, row1, q, 2, c1 * v1.z);
        tile_add(tile, row1, q, 3, c1 * v1.w);
    }
    for (; g < M; g += 64) {
        uint2 r = mine[g];
        const float4 v = *reinterpret_cast<const float4*>(
            x + (size_t)(r.y & 0xFFFFFFu) * F_DIM + q);
        float c = __uint_as_float(r.x);
        int row = (r.y >> 24) & 63;
        tile_add(tile, row, q, 0, c * v.x);
        tile_add(tile, row, q, 1, c * v.y);
        tile_add(tile, row, q, 2, c * v.z);
        tile_add(tile, row, q, 3, c * v.w);
    }
    __syncthreads();

    // flush (un-rotate), coalesced: 2048 floats by 512 threads
    const int node0 = coarse * NPB_C + (int)sub * NPB_F;
    for (int i = t; i < NPB_F * F_DIM; i += AGG_THREADS) {
        int rr  = i >> 5;
        int col = i & 31;
        int n   = node0 + rr;
        if (n < N_NODES)
            out[(size_t)n * F_DIM + col] = tile[(rr << 5) + ((col + rr) & 31)];
    }
}

// ---------------- fallback (R0): plain atomic scatter ----------------
__global__ __launch_bounds__(256) void gnn_scatter_atomic(
    const float* __restrict__ x, const int* __restrict__ src,
    const int* __restrict__ dst, const float* __restrict__ ew,
    const float* __restrict__ w_mp, float* __restrict__ out)
{
    const float w = w_mp[0];
    int gid = blockIdx.x * blockDim.x + threadIdx.x;
    int e = gid >> 3;
    int qq = (gid & 7) * 4;
    if (e >= N_EDGES) return;
    int s = src[e];
    int d = dst[e];
    float c = w * ew[e];
    const float4 xv = *reinterpret_cast<const float4*>(x + (size_t)s * F_DIM + qq);
    float* op = out + (size_t)d * F_DIM + qq;
    atomicAdd(op + 0, c * xv.x);
    atomicAdd(op + 1, c * xv.y);
    atomicAdd(op + 2, c * xv.z);
    atomicAdd(op + 3, c * xv.w);
}

extern "C" void kernel_launch(void* const* d_in, const int* in_sizes, int n_in,
                              void* d_out, int out_size, void* d_ws, size_t ws_size,
                              hipStream_t stream) {
    const float* x    = (const float*)d_in[0];
    const int*   ei   = (const int*)d_in[1];   // [2, E]: src row, then dst row
    const float* ew   = (const float*)d_in[2];
    const float* w_mp = (const float*)d_in[3];
    float* out = (float*)d_out;

    const int* src = ei;
    const int* dst = ei + N_EDGES;

    if (ws_size < WS_NEEDED) {
        hipMemsetAsync(d_out, 0, (size_t)out_size * sizeof(float), stream);
        int total = N_EDGES * 8;
        gnn_scatter_atomic<<<(total + 255) / 256, 256, 0, stream>>>(
            x, src, dst, ew, w_mp, out);
        return;
    }

    char* ws = (char*)d_ws;
    int*   gcursor = (int*)(ws + WS_CURSOR);
    uint2* records = (uint2*)(ws + WS_RECORDS);

    init_cursors<<<(NB_C + 255) / 256, 256, 0, stream>>>(gcursor);
    bin_edges<<<BIN_BLOCKS, BIN_THREADS, 0, stream>>>(src, dst, ew, w_mp,
                                                      gcursor, records);
    gather_nosort<<<NB_C * SUBS, AGG_THREADS, 0, stream>>>(gcursor, records, x, out);
    // gather_nosort writes every out element -> no d_out memset needed
}

// Round 7
// 128.939 us; speedup vs baseline: 3.1088x; 3.1088x over previous
//
#include <hip/hip_runtime.h>

// toy_gnn scatter-add: out[dst[e], f] += w_mp * edge_weight[e] * x[src[e], f]
// N=100000, E=1600000, F=32, fp32.
//
// Round 7: coarse bin (R4 shape) + fused compact/sort/register-gather (R5/R6
// proven pieces).
//   R6 post-mortem: LDS fp32 atomic accumulation via a generic pointer
//   lowered to slow flat atomics (312us, VALUBusy 4%) -- never again; the
//   fast accumulate is registers (R5). R5 post-mortem: fine binning (64-node
//   buckets) regressed write density to 21B runs.
//   Now: bin into 391 coarse buckets (21-record=168B dense runs), then 4
//   blocks per bucket (1564 blocks): ballot-compact own quarter -> LDS
//   counting-sort by node (shuffle scan) -> 8 thr/node register gather with
//   4-way unrolled x-loads -> one coalesced 128B store per node.

constexpr int N_NODES = 100000;
constexpr int N_EDGES = 1600000;
constexpr int F_DIM   = 32;

// ---- binning (coarse) ----
constexpr int NPB_C = 256;                           // nodes per coarse bucket
constexpr int NB_C  = (N_NODES + NPB_C - 1) / NPB_C; // 391
constexpr int CAP_C = 4608;                          // mean 4096 + 8 sigma(64)

constexpr int BIN_THREADS = 512;
constexpr int BIN_EPT     = 16;
constexpr int BIN_CHUNK   = BIN_THREADS * BIN_EPT;                  // 8192
constexpr int BIN_BLOCKS  = (N_EDGES + BIN_CHUNK - 1) / BIN_CHUNK;  // 196

// ---- fused gather ----
constexpr int SUBS  = 4;                             // blocks per coarse bucket
constexpr int NPB_F = NPB_C / SUBS;                  // 64 nodes per block
constexpr int MCAP  = 1344;                          // mean 1024 + 10 sigma(32)
constexpr int AGG_THREADS = 512;
constexpr int RPT = (MCAP + AGG_THREADS - 1) / AGG_THREADS;  // 3

// ---------------- workspace layout (bytes) ----------------
constexpr size_t WS_CURSOR  = 0;                     // NB_C ints
constexpr size_t WS_RECORDS = 4096;                  // NB_C*CAP_C uint2
constexpr size_t WS_NEEDED  = WS_RECORDS + (size_t)NB_C * CAP_C * 8;  // ~14.4 MB

__global__ __launch_bounds__(256) void init_cursors(int* __restrict__ gcursor)
{
    int i = blockIdx.x * 256 + threadIdx.x;
    if (i < NB_C) gcursor[i] = i * CAP_C;
}

__global__ __launch_bounds__(BIN_THREADS) void bin_edges(
    const int* __restrict__ src, const int* __restrict__ dst,
    const float* __restrict__ ew, const float* __restrict__ w_mp,
    int* __restrict__ gcursor, uint2* __restrict__ records)
{
    __shared__ int lhist[NB_C];
    __shared__ int lbase[NB_C];
    if (threadIdx.x < NB_C) lhist[threadIdx.x] = 0;
    __syncthreads();

    const float w = w_mp[0];
    const int base_e = blockIdx.x * BIN_CHUNK;
    int   bkt[BIN_EPT];
    uint2 rec[BIN_EPT];

    #pragma unroll
    for (int i = 0; i < BIN_EPT; ++i) {
        int e = base_e + threadIdx.x + i * BIN_THREADS;
        bkt[i] = -1;
        if (e < N_EDGES) {
            int d = dst[e];
            int b = d >> 8;                     // coarse bucket (256 nodes)
            bkt[i] = b;
            rec[i].x = __float_as_uint(w * ew[e]);
            rec[i].y = (unsigned)src[e] | ((unsigned)(d & 255) << 24);
            atomicAdd(&lhist[b], 1);
        }
    }
    __syncthreads();

    if (threadIdx.x < NB_C) {
        int c = lhist[threadIdx.x];
        lbase[threadIdx.x] = c ? atomicAdd(&gcursor[threadIdx.x], c) : 0;
        lhist[threadIdx.x] = 0;
    }
    __syncthreads();

    #pragma unroll
    for (int i = 0; i < BIN_EPT; ++i) {
        int b = bkt[i];
        if (b >= 0) {
            int pos = lbase[b] + atomicAdd(&lhist[b], 1);
            if (pos < (b + 1) * CAP_C)          // overflow guard (8-sigma margin)
                records[pos] = rec[i];
        }
    }
}

__global__ __launch_bounds__(AGG_THREADS) void sort_gather(
    const int*   __restrict__ gcursor,
    const uint2* __restrict__ records,
    const float* __restrict__ x,
    float*       __restrict__ out)
{
    __shared__ uint2 mine[MCAP];       // 10.5 KB compacted records (this sub)
    __shared__ uint2 sorted[MCAP];     // 10.5 KB node-sorted records
    __shared__ int   hist[NPB_F];
    __shared__ int   offs[NPB_F + 1];
    __shared__ int   cursor[NPB_F];
    __shared__ int   mcount;

    const int coarse   = blockIdx.x >> 2;
    const unsigned sub = blockIdx.x & 3;
    const int t        = threadIdx.x;
    const int lane     = t & 63;

    if (t < NPB_F) hist[t] = 0;
    if (t == 0) mcount = 0;
    __syncthreads();

    // --- compact this sub's records (wave-aggregated slot allocation) ---
    const int rbase = coarse * CAP_C;
    const int cnt   = min(gcursor[coarse] - rbase, CAP_C);
    for (int j = t; j < cnt; j += AGG_THREADS) {
        uint2 r = records[rbase + j];
        bool match = (r.y >> 30) == sub;        // dl>>6 == sub
        unsigned long long m = __ballot(match);
        if (m) {
            int lead = __ffsll(m) - 1;
            int base = 0;
            if (lane == lead) base = atomicAdd(&mcount, __popcll(m));
            base = __shfl(base, lead, 64);
            if (match) {
                int slot = base + __popcll(m & ((1ull << lane) - 1));
                if (slot < MCAP) mine[slot] = r;   // 10-sigma margin
            }
        }
    }
    __syncthreads();

    // --- counting sort by node-in-sub (6 bits) ---
    const int M = min(mcount, MCAP);
    uint2 rec[RPT];
    #pragma unroll
    for (int i = 0; i < RPT; ++i) {
        int j = t + i * AGG_THREADS;
        rec[i].y = 0xFFFFFFFFu;                 // "empty"
        if (j < M) {
            rec[i] = mine[j];
            atomicAdd(&hist[(rec[i].y >> 24) & 63], 1);
        }
    }
    __syncthreads();

    if (t < 64) {                               // wave 0: shuffle scan
        int v   = hist[t];
        int inc = v;
        #pragma unroll
        for (int d = 1; d < 64; d <<= 1) {
            int o = __shfl_up(inc, d, 64);
            if (t >= d) inc += o;
        }
        offs[t + 1] = inc;
        if (t == 0) offs[0] = 0;
        cursor[t] = inc - v;                    // exclusive prefix
    }
    __syncthreads();

    #pragma unroll
    for (int i = 0; i < RPT; ++i) {
        if (rec[i].y != 0xFFFFFFFFu) {
            int slot = atomicAdd(&cursor[(rec[i].y >> 24) & 63], 1);
            sorted[slot] = rec[i];
        }
    }
    __syncthreads();

    // --- gather: 8 threads/node, register acc, 4-way unrolled x-loads ---
    const int node  = t >> 3;
    const int q     = (t & 7) * 4;
    const int gnode = coarse * NPB_C + (int)sub * NPB_F + node;
    if (gnode >= N_NODES) return;

    int j  = offs[node];
    int je = offs[node + 1];
    float4 acc = make_float4(0.f, 0.f, 0.f, 0.f);

    for (; j + 4 <= je; j += 4) {
        uint2 r0 = sorted[j + 0];
        uint2 r1 = sorted[j + 1];
        uint2 r2 = sorted[j + 2];
        uint2 r3 = sorted[j + 3];
        const float4 v0 = *reinterpret_cast<const float4*>(
            x + (size_t)(r0.y & 0xFFFFFFu) * F_DIM + q);
        const float4 v1 = *reinterpret_cast<const float4*>(
            x + (size_t)(r1.y & 0xFFFFFFu) * F_DIM + q);
        const float4 v2 = *reinterpret_cast<const float4*>(
            x + (size_t)(r2.y & 0xFFFFFFu) * F_DIM + q);
        const float4 v3 = *reinterpret_cast<const float4*>(
            x + (size_t)(r3.y & 0xFFFFFFu) * F_DIM + q);
        float c0 = __uint_as_float(r0.x), c1 = __uint_as_float(r1.x);
        float c2 = __uint_as_float(r2.x), c3 = __uint_as_float(r3.x);
        acc.x += c0 * v0.x + c1 * v1.x + c2 * v2.x + c3 * v3.x;
        acc.y += c0 * v0.y + c1 * v1.y + c2 * v2.y + c3 * v3.y;
        acc.z += c0 * v0.z + c1 * v1.z + c2 * v2.z + c3 * v3.z;
        acc.w += c0 * v0.w + c1 * v1.w + c2 * v2.w + c3 * v3.w;
    }
    for (; j < je; ++j) {
        uint2 r = sorted[j];
        float c = __uint_as_float(r.x);
        const float4 v = *reinterpret_cast<const float4*>(
            x + (size_t)(r.y & 0xFFFFFFu) * F_DIM + q);
        acc.x += c * v.x;
        acc.y += c * v.y;
        acc.z += c * v.z;
        acc.w += c * v.w;
    }
    *reinterpret_cast<float4*>(out + (size_t)gnode * F_DIM + q) = acc;
}

// ---------------- fallback (R0): plain atomic scatter ----------------
__global__ __launch_bounds__(256) void gnn_scatter_atomic(
    const float* __restrict__ x, const int* __restrict__ src,
    const int* __restrict__ dst, const float* __restrict__ ew,
    const float* __restrict__ w_mp, float* __restrict__ out)
{
    const float w = w_mp[0];
    int gid = blockIdx.x * blockDim.x + threadIdx.x;
    int e = gid >> 3;
    int qq = (gid & 7) * 4;
    if (e >= N_EDGES) return;
    int s = src[e];
    int d = dst[e];
    float c = w * ew[e];
    const float4 xv = *reinterpret_cast<const float4*>(x + (size_t)s * F_DIM + qq);
    float* op = out + (size_t)d * F_DIM + qq;
    atomicAdd(op + 0, c * xv.x);
    atomicAdd(op + 1, c * xv.y);
    atomicAdd(op + 2, c * xv.z);
    atomicAdd(op + 3, c * xv.w);
}

extern "C" void kernel_launch(void* const* d_in, const int* in_sizes, int n_in,
                              void* d_out, int out_size, void* d_ws, size_t ws_size,
                              hipStream_t stream) {
    const float* x    = (const float*)d_in[0];
    const int*   ei   = (const int*)d_in[1];   // [2, E]: src row, then dst row
    const float* ew   = (const float*)d_in[2];
    const float* w_mp = (const float*)d_in[3];
    float* out = (float*)d_out;

    const int* src = ei;
    const int* dst = ei + N_EDGES;

    if (ws_size < WS_NEEDED) {
        hipMemsetAsync(d_out, 0, (size_t)out_size * sizeof(float), stream);
        int total = N_EDGES * 8;
        gnn_scatter_atomic<<<(total + 255) / 256, 256, 0, stream>>>(
            x, src, dst, ew, w_mp, out);
        return;
    }

    char* ws = (char*)d_ws;
    int*   gcursor = (int*)(ws + WS_CURSOR);
    uint2* records = (uint2*)(ws + WS_RECORDS);

    init_cursors<<<(NB_C + 255) / 256, 256, 0, stream>>>(gcursor);
    bin_edges<<<BIN_BLOCKS, BIN_THREADS, 0, stream>>>(src, dst, ew, w_mp,
                                                      gcursor, records);
    sort_gather<<<NB_C * SUBS, AGG_THREADS, 0, stream>>>(gcursor, records, x, out);
    // sort_gather writes every out element -> no d_out memset needed
}